// Round 5
// baseline (499.166 us; speedup 1.0000x reference)
//
#include <hip/hip_runtime.h>

#define NN 100000
#define MM 8
#define KK 256
#define DD 64
#define BROWS 64
#define NTILES ((NN + BROWS - 1) / BROWS)   // 1563

typedef _Float16 half8 __attribute__((ext_vector_type(8)));
typedef float    f32x4 __attribute__((ext_vector_type(4)));

// ---------------------------------------------------------------------------
// ws layout (bytes):
//   [0,      256K)  cb_hi  half8[MM*8*256]   chunk-major: idx = m*2048 + c*256 + k
//   [256K,   512K)  cb_lo  (scaled x2048)
//   [512K,   520K)  csq    float[MM*KK]
// ---------------------------------------------------------------------------

__global__ __launch_bounds__(256) void pq_prep_kernel(
    const float* __restrict__ cb, half8* __restrict__ whi,
    half8* __restrict__ wlo, float* __restrict__ csq)
{
    const int t = blockIdx.x * 256 + threadIdx.x;      // 0..16383
    const int m = t >> 11, rest = t & 2047;
    const int c = rest >> 8, k = rest & 255;
    const float* src = cb + ((size_t)(m * KK + k)) * DD + c * 8;
    half8 h, l;
#pragma unroll
    for (int j = 0; j < 8; ++j) {
        float v = src[j];
        _Float16 hi = (_Float16)v;
        h[j] = hi;
        l[j] = (_Float16)((v - (float)hi) * 2048.0f);
    }
    whi[t] = h;
    wlo[t] = l;

    if (t < MM * KK) {
        const float* cr = cb + (size_t)t * DD;
        float s0 = 0.f, s1 = 0.f, s2 = 0.f, s3 = 0.f;
#pragma unroll
        for (int d = 0; d < DD; d += 4) {
            s0 = fmaf(cr[d + 0], cr[d + 0], s0);
            s1 = fmaf(cr[d + 1], cr[d + 1], s1);
            s2 = fmaf(cr[d + 2], cr[d + 2], s2);
            s3 = fmaf(cr[d + 3], cr[d + 3], s3);
        }
        csq[t] = (s0 + s1) + (s2 + s3);
    }
}

// Main, R5: THIN-WAVE restructure. 4 rounds proved the k-loop schedule is
// not the bottleneck (LDS-staged / direct / depth-2 / interleaved all ~200us,
// ~80% wave-stall at ~2.5 resident waves/SIMD). Lever never pulled: work
// grain. Block = 64 rows, each wave = 16 rows x 256 k (rb=1). Per-wave regs
// ~60-75 -> launch_bounds(256,6): ~2.4x resident waves for latency hiding.
//
// Packed-key tracking: kt (4 bits) stuffed into low mantissa bits of d
// (perturb <= 15 ulp ~= 3.6e-4 << DELTA margin; any argmin flip this could
// cause implies gap < 8e-4 -> exact-rescore triggers and fixes it, so the
// fast path stays numpy-exact). Replaces cmp+cndmask chains with min/max,
// kills k1v tracking entirely.
#define DELTA 4.0e-3f

#define MFMA16(A, B, C) __builtin_amdgcn_mfma_f32_16x16x32_f16(A, B, C, 0, 0, 0)

__global__ __launch_bounds__(256, 6) void pq_main_kernel(
    const float* __restrict__ x, const half8* __restrict__ whi,
    const half8* __restrict__ wlo, const float* __restrict__ csqg,
    const float* __restrict__ cbf, float* __restrict__ qout,
    float* __restrict__ idout)
{
    __shared__ float csq_s[KK];     // 1 KB
    __shared__ int   cand_k[BROWS]; // 256 B

    const int m   = blockIdx.y;
    const int n0  = blockIdx.x * BROWS;
    const int tid = threadIdx.x;
    const int w = tid >> 6, L = tid & 63;
    const int q = L >> 4, ci = L & 15;

    csq_s[tid] = csqg[m * KK + tid];

    // A fragments (one 16-row window per wave): d = t*32 + q*8 + j on BOTH
    // operands -> k-slot permutation cancels.
    half8 Ah[2], Al[2];
    {
        int n = n0 + w * 16 + ci;
        if (n > NN - 1) n = NN - 1;                    // tail clamp (writes guarded)
        const float4* xp = (const float4*)(x + (size_t)n * (MM * DD) + m * DD);
#pragma unroll
        for (int t = 0; t < 2; ++t) {
            float4 v0 = xp[t * 8 + q * 2 + 0];
            float4 v1 = xp[t * 8 + q * 2 + 1];
            float vs[8] = {v0.x, v0.y, v0.z, v0.w, v1.x, v1.y, v1.z, v1.w};
#pragma unroll
            for (int j = 0; j < 8; ++j) {
                _Float16 hi = (_Float16)vs[j];
                Ah[t][j] = hi;
                Al[t][j] = (_Float16)((vs[j] - (float)hi) * 2048.0f);
            }
        }
    }

    // packed-key trackers: m1 = best key, m2 = second-best key, per row slot r
    float m1[4], m2[4];
#pragma unroll
    for (int r = 0; r < 4; ++r) { m1[r] = 3.4e38f; m2[r] = 3.4e38f; }

    // Per-lane B fragment pointers: c-chunk = q (low 32 dims) and 4+q (high).
    const half8* bh0p = whi + m * 2048 + q * 256;
    const half8* bh1p = whi + m * 2048 + (4 + q) * 256;
    const half8* bl0p = wlo + m * 2048 + q * 256;
    const half8* bl1p = wlo + m * 2048 + (4 + q) * 256;

    __syncthreads();                                   // csq_s ready

    const f32x4 z = {0.f, 0.f, 0.f, 0.f};

#pragma unroll 2
    for (int kt = 0; kt < 16; ++kt) {
        const int o = kt * 16 + ci;
        half8 bh0 = bh0p[o], bh1 = bh1p[o], bl0 = bl0p[o], bl1 = bl1p[o];

        f32x4 acc1 = z, acc2 = z;
        acc1 = MFMA16(Ah[0], bh0, acc1);
        acc1 = MFMA16(Ah[1], bh1, acc1);
        acc2 = MFMA16(Ah[0], bl0, acc2);
        acc2 = MFMA16(Ah[1], bl1, acc2);
        acc2 = MFMA16(Al[0], bh0, acc2);
        acc2 = MFMA16(Al[1], bh1, acc2);

        // dist(sans xsq) = csq - 2*(acc1 + acc2/2048); C/D: col=lane&15, row=q*4+r
        const int k = kt * 16 + ci;
        const float cq = csq_s[k];
#pragma unroll
        for (int r = 0; r < 4; ++r) {
            float cross = acc1[r] + acc2[r] * (1.0f / 2048.0f);
            float d = cq - 2.0f * cross;
            // stuff kt into low 4 mantissa bits -> key ~= d (+-15 ulp)
            unsigned du = __float_as_uint(d);
            float key = __uint_as_float((du & 0xFFFFFFF0u) | (unsigned)kt);
            float t2 = fmaxf(m1[r], key);
            m2[r] = fminf(m2[r], t2);
            m1[r] = fminf(m1[r], key);
        }
    }

    // Finalize each of the 4 row-slots: butterfly argmin over packed keys;
    // near-ties -> exact fp32 rescore (R1 arithmetic, numpy-exact).
#pragma unroll
    for (int r = 0; r < 4; ++r) {
        float key = m1[r];
        int   kk  = (int)(__float_as_uint(key) & 15u) * 16 + ci;
        for (int mask = 1; mask < 16; mask <<= 1) {
            float ks = __shfl_xor(key, mask);
            int   kx = __shfl_xor(kk, mask);
            if (ks < key || (ks == key && kx < kk)) { key = ks; kk = kx; }
        }
        const float thr = key + DELTA;                 // key == packed dmin, uniform
        int cnt = (m1[r] <= thr ? 1 : 0) + (m2[r] <= thr ? 1 : 0);
        for (int mask = 1; mask < 16; mask <<= 1) cnt += __shfl_xor(cnt, mask);

        const int n = n0 + w * 16 + q * 4 + r;
        int kfin = kk;
        if (cnt > 1 && n < NN) {                       // rare exact path (q-group uniform)
            const float* xr = x + (size_t)n * (MM * DD) + m * DD;
            float s0 = 0.f, s1 = 0.f, s2 = 0.f, s3 = 0.f;
            for (int dd = 0; dd < DD; dd += 4) {
                s0 = fmaf(xr[dd + 0], xr[dd + 0], s0);
                s1 = fmaf(xr[dd + 1], xr[dd + 1], s1);
                s2 = fmaf(xr[dd + 2], xr[dd + 2], s2);
                s3 = fmaf(xr[dd + 3], xr[dd + 3], s3);
            }
            const float xsq = (s0 + s1) + (s2 + s3);
            float bd = 3.4e38f; int bk = 0;
            for (int j = 0; j < 16; ++j) {             // lane ci: k = ci + 16j (ascending)
                const int kc = ci + 16 * j;
                const float* c0 = cbf + ((size_t)(m * KK + kc)) * DD;
                float a0 = 0.f, a1 = 0.f;
                for (int dd = 0; dd < DD; dd += 2) {
                    a0 = fmaf(c0[dd + 0], xr[dd + 0], a0);
                    a1 = fmaf(c0[dd + 1], xr[dd + 1], a1);
                }
                const float dist = (xsq - 2.f * (a0 + a1)) + csq_s[kc];
                if (dist < bd) { bd = dist; bk = kc; } // strict <, ascending k
            }
            for (int mask = 1; mask < 16; mask <<= 1) {
                float db = __shfl_xor(bd, mask);
                int   kb = __shfl_xor(bk, mask);
                if (db < bd || (db == bd && kb < bk)) { bd = db; bk = kb; }
            }
            kfin = bk;
        }
        if (ci == r) cand_k[w * 16 + q * 4 + r] = kfin;
    }
    __syncthreads();

    if (tid < BROWS) {
        int n = n0 + tid;
        if (n < NN) idout[(size_t)m * NN + n] = (float)cand_k[tid];
    }
#pragma unroll
    for (int i = 0; i < 4; ++i) {
        int row = i * 16 + (tid >> 4);
        int n = n0 + row;
        if (n < NN) {
            int k = cand_k[row];
            int j = tid & 15;
            float4 v = ((const float4*)cbf)[(m * KK + k) * 16 + j];
            ((float4*)(qout + (size_t)n * (MM * DD) + m * DD))[j] = v;
        }
    }
}

extern "C" void kernel_launch(void* const* d_in, const int* in_sizes, int n_in,
                              void* d_out, int out_size, void* d_ws, size_t ws_size,
                              hipStream_t stream)
{
    const float* x  = (const float*)d_in[0];
    const float* cb = (const float*)d_in[1];

    float* qout  = (float*)d_out;
    float* idout = qout + (size_t)NN * (MM * DD);

    half8* whi = (half8*)d_ws;
    half8* wlo = (half8*)((char*)d_ws + 256 * 1024);
    float* csq = (float*)((char*)d_ws + 512 * 1024);

    pq_prep_kernel<<<dim3(64), dim3(256), 0, stream>>>(cb, whi, wlo, csq);

    pq_main_kernel<<<dim3(NTILES, MM), dim3(256), 0, stream>>>(
        x, whi, wlo, csq, cb, qout, idout);
}